// Round 5
// baseline (955.811 us; speedup 1.0000x reference)
//
#include <hip/hip_runtime.h>
#include <hip/hip_bf16.h>

typedef __hip_bfloat16 bf16;

// Problem constants
constexpr int Nn  = 4;
constexpr int Ci  = 256;
constexpr int Cc  = 64;
constexpr int Hh  = 128;
constexpr int Ww  = 128;
constexpr int HWh = Hh * Ww;
constexpr int Hl  = 64;
constexpr int Wl  = 64;
constexpr int HWl = Hl * Wl;
constexpr int K2L = 25;
constexpr int K2H = 9;

// Output element offsets (in output elements): [mask | hr_out | lr_out]
constexpr size_t OFF_HR   = (size_t)Nn * K2L * HWh;            // 1,638,400
constexpr size_t OFF_LR   = OFF_HR + (size_t)Nn * Ci * HWh;    // 18,415,616

// Arena A (inside out_lr region; capacity 8,388,608 f32 even in bf16 mode:
// region = 16,777,216 output elements).
constexpr size_t A_CHF    = 0;        // 4,194,304  [s2-s5']
constexpr size_t A_MLRHR  = 0;        // 1,638,400  [s6-s9']  (chf dead)
constexpr size_t A_MLRLL  = 1700000;  //   409,600  [s7-s9']
constexpr size_t A_CLFE2  = 2200000;  //   147,456  [s7-s11]
constexpr size_t A_MHR2   = 0;        //   589,824  [s11-s14'] (mlrhr dead)
constexpr size_t A_WHR    = 7800000;  // 16,384 weights, live s1-s7
constexpr size_t A_WLR    = 7820000;  // 16,384
constexpr size_t A_WENC   = 7840000;  // 14,400
constexpr size_t A_WENC2  = 7860000;  //  5,184
constexpr size_t A_BHR    = 7870000;  // 64
constexpr size_t A_BLR    = 7870100;  // 64
constexpr size_t A_BENC   = 7870200;  // 64
constexpr size_t A_BENC2  = 7870300;  // 64   -> top 7,870,364 < 8,388,608 OK

// Arena B (inside out_hr region)
constexpr size_t B_CLF    = 0;        // 1,048,576  [s2-s7]
constexpr size_t B_CHF2   = 1100000;  // 4,194,304  [s5'-s6] -> top 5,294,304
constexpr size_t B_MHRHR  = 5300000;  //   589,824  [s3-s11] -> top 5,889,824 OK
constexpr size_t B_MLR    = 0;        // 1,638,400  [s9'-s10] (clf/chf2 dead)

__device__ __forceinline__ float tofloat(float v) { return v; }
__device__ __forceinline__ float tofloat(bf16 v) { return __bfloat162float(v); }

template<typename T> __device__ __forceinline__ T fromfloat(float v);
template<> __device__ __forceinline__ float fromfloat<float>(float v) { return v; }
template<> __device__ __forceinline__ bf16  fromfloat<bf16>(float v)  { return __float2bfloat16(v); }

// f32 scratch pointer inside an output region (region offsets are in OUTPUT
// elements, so byte addresses depend on the detected output dtype).
__device__ __forceinline__ float* scrp(void* d, int f32, size_t reg, size_t off) {
  float* b = f32 ? ((float*)d + reg) : (float*)((bf16*)d + reg);
  return b + off;
}

// ---------------------------------------------------------------------------
// dtype detector: flag=1 means f32 I/O, flag=0 means bf16 I/O.
// ---------------------------------------------------------------------------
__global__ void detect_dtype(const void* feat, int* flag) {
  __shared__ int s;
  if (threadIdx.x == 0) s = 0;
  __syncthreads();
  unsigned short b = ((const unsigned short*)feat)[threadIdx.x];
  float v = __uint_as_float(((unsigned int)b) << 16);
  if (!(fabsf(v) < 1000.0f)) atomicOr(&s, 1);
  __syncthreads();
  if (threadIdx.x == 0) *flag = s;
}

// ---------------------------------------------------------------------------
// Weight prep: 1x1 [co][ci] -> [ci][co]; 3x3 [ko][ci][9] -> [ci][KO][9]
// ---------------------------------------------------------------------------
template<typename T>
__device__ void prep_body(const T* hw, const T* hb, const T* lw, const T* lb,
                          const T* ew, const T* eb, const T* e2w, const T* e2b,
                          float* whr, float* wlr, float* wenc, float* wenc2,
                          float* bhr, float* blr, float* benc, float* benc2) {
  int tid = blockIdx.x * 256 + threadIdx.x, nt = gridDim.x * 256;
  for (int i = tid; i < Cc * Ci; i += nt) {
    int co = i / Ci, ci = i % Ci;
    whr[ci * Cc + co] = tofloat(hw[i]);
    wlr[ci * Cc + co] = tofloat(lw[i]);
  }
  for (int i = tid; i < K2L * Cc * 9; i += nt) {
    int ko = i / (Cc * 9), r = i % (Cc * 9), ci = r / 9, k = r % 9;
    wenc[(ci * K2L + ko) * 9 + k] = tofloat(ew[i]);
  }
  for (int i = tid; i < K2H * Cc * 9; i += nt) {
    int ko = i / (Cc * 9), r = i % (Cc * 9), ci = r / 9, k = r % 9;
    wenc2[(ci * K2H + ko) * 9 + k] = tofloat(e2w[i]);
  }
  if (tid < Cc)  { bhr[tid] = tofloat(hb[tid]); blr[tid] = tofloat(lb[tid]); }
  if (tid < K2L) benc[tid]  = tofloat(eb[tid]);
  if (tid < K2H) benc2[tid] = tofloat(e2b[tid]);
}

__global__ void prep_weights(const int* flag, void* dout,
                             const void* hw, const void* hb, const void* lw, const void* lb,
                             const void* ew, const void* eb, const void* e2w, const void* e2b) {
  int f32 = *flag;
  float* whr   = scrp(dout, f32, OFF_LR, A_WHR);
  float* wlr   = scrp(dout, f32, OFF_LR, A_WLR);
  float* wenc  = scrp(dout, f32, OFF_LR, A_WENC);
  float* wenc2 = scrp(dout, f32, OFF_LR, A_WENC2);
  float* bhr   = scrp(dout, f32, OFF_LR, A_BHR);
  float* blr   = scrp(dout, f32, OFF_LR, A_BLR);
  float* benc  = scrp(dout, f32, OFF_LR, A_BENC);
  float* benc2 = scrp(dout, f32, OFF_LR, A_BENC2);
  if (f32) prep_body<float>((const float*)hw, (const float*)hb, (const float*)lw, (const float*)lb,
                            (const float*)ew, (const float*)eb, (const float*)e2w, (const float*)e2b,
                            whr, wlr, wenc, wenc2, bhr, blr, benc, benc2);
  else     prep_body<bf16>((const bf16*)hw, (const bf16*)hb, (const bf16*)lw, (const bf16*)lb,
                           (const bf16*)ew, (const bf16*)eb, (const bf16*)e2w, (const bf16*)e2b,
                           whr, wlr, wenc, wenc2, bhr, blr, benc, benc2);
}

// ---------------------------------------------------------------------------
// 1x1 conv: block = 256 threads, 512 px x 16 co; thread: 2 px x 16 co.
// grid (P/512, Nn, 4 co-groups). All waves share one co-group -> weight rows
// are wave-uniform scalar loads from a block-shared 16 KB working set.
// ---------------------------------------------------------------------------
template<typename T>
__device__ void conv1x1_body(const T* __restrict__ in, const float* __restrict__ wt,
                             const float* __restrict__ bias, float* __restrict__ out,
                             int P, int n, int co0) {
  const int tid = threadIdx.x;
  const int px = blockIdx.x * 512 + (tid >> 6) * 64 + (tid & 63);
  const T* inp = in + (size_t)n * Ci * P + px;

  float acc[2][16];
  #pragma unroll
  for (int c = 0; c < 16; ++c) {
    float b = bias[co0 + c];
    acc[0][c] = b; acc[1][c] = b;
  }
  #pragma unroll 4
  for (int ci = 0; ci < Ci; ++ci) {
    float v0 = tofloat(inp[(size_t)ci * P]);
    float v1 = tofloat(inp[(size_t)ci * P + 256]);
    const float* wr = wt + ci * Cc + co0;
    #pragma unroll
    for (int c = 0; c < 16; ++c) {
      float wv = wr[c];
      acc[0][c] = fmaf(v0, wv, acc[0][c]);
      acc[1][c] = fmaf(v1, wv, acc[1][c]);
    }
  }
  float* op = out + (size_t)n * Cc * P + px;
  #pragma unroll
  for (int c = 0; c < 16; ++c) {
    op[(size_t)(co0 + c) * P]       = acc[0][c];
    op[(size_t)(co0 + c) * P + 256] = acc[1][c];
  }
}

__global__ __launch_bounds__(256) void conv1x1_k(const int* flag, void* dout, const void* in,
                                                 size_t w_off, size_t b_off,
                                                 size_t o_reg, size_t o_off, int P) {
  int f32 = *flag;
  const float* wt   = scrp(dout, f32, OFF_LR, w_off);
  const float* bias = scrp(dout, f32, OFF_LR, b_off);
  float* out        = scrp(dout, f32, o_reg, o_off);
  const int n = blockIdx.y, co0 = blockIdx.z * 16;
  if (f32) conv1x1_body<float>((const float*)in, wt, bias, out, P, n, co0);
  else     conv1x1_body<bf16>((const bf16*)in, wt, bias, out, P, n, co0);
}

// ---------------------------------------------------------------------------
// 3x3 conv, pad=1, ko-group split: grid (w/16, h/16, Nn*(KO/KOG)).
// Input chunk (16ci x 18x18) AND this group's weights (16ci x KOG x 9) staged
// in LDS; weight reads are wave-uniform LDS broadcasts.
// ---------------------------------------------------------------------------
template<int KO, int KOG>
__global__ __launch_bounds__(256) void conv3x3_k(const int* flag, void* dout,
                                                 size_t i_reg, size_t i_off,
                                                 size_t w_off, size_t b_off,
                                                 size_t o_reg, size_t o_off, int hh, int ww) {
  constexpr int NG = KO / KOG;
  int f32 = *flag;
  const float* in   = scrp(dout, f32, i_reg, i_off);
  const float* wt   = scrp(dout, f32, OFF_LR, w_off);
  const float* bias = scrp(dout, f32, OFF_LR, b_off);
  float* out        = scrp(dout, f32, o_reg, o_off);

  __shared__ float tile[16 * 324];
  __shared__ float wl[16 * KOG * 9];
  const int tid = threadIdx.x;
  const int tx = tid & 15, ty = tid >> 4;
  const int bx = blockIdx.x * 16, by = blockIdx.y * 16;
  const int n = blockIdx.z / NG, g = blockIdx.z % NG;
  const int ko0 = g * KOG;

  float acc[KOG];
  #pragma unroll
  for (int kg = 0; kg < KOG; ++kg) acc[kg] = bias[ko0 + kg];

  for (int cc = 0; cc < Cc; cc += 16) {
    __syncthreads();
    for (int i = tid; i < 16 * 324; i += 256) {
      int ci = i / 324, r = i % 324, yy = r / 18, xx = r % 18;
      int gy = by + yy - 1, gx = bx + xx - 1;
      float v = 0.f;
      if (gy >= 0 && gy < hh && gx >= 0 && gx < ww)
        v = in[(((size_t)n * Cc + cc + ci) * hh + gy) * ww + gx];
      tile[i] = v;
    }
    for (int i = tid; i < 16 * KOG * 9; i += 256) {
      int ci = i / (KOG * 9), r = i % (KOG * 9);
      wl[i] = wt[((size_t)(cc + ci) * KO + ko0) * 9 + r];
    }
    __syncthreads();
    for (int ci = 0; ci < 16; ++ci) {
      float nb[9];
      #pragma unroll
      for (int dy = 0; dy < 3; ++dy)
        #pragma unroll
        for (int dx = 0; dx < 3; ++dx)
          nb[dy * 3 + dx] = tile[ci * 324 + (ty + dy) * 18 + tx + dx];
      const float* w = &wl[ci * KOG * 9];
      #pragma unroll
      for (int kg = 0; kg < KOG; ++kg)
        #pragma unroll
        for (int k = 0; k < 9; ++k)
          acc[kg] = fmaf(w[kg * 9 + k], nb[k], acc[kg]);
    }
  }
  const size_t ob = (((size_t)n * KO + ko0) * hh + by + ty) * ww + bx + tx;
  #pragma unroll
  for (int kg = 0; kg < KOG; ++kg) out[ob + (size_t)kg * hh * ww] = acc[kg];
}

// ---------------------------------------------------------------------------
// s10: softmax over 25 channels -> FINAL output 0 (dtype by flag).
// 64-thread blocks, grid (HWh/64, Nn) = 1024 blocks.
// ---------------------------------------------------------------------------
__global__ __launch_bounds__(64) void softmax25_k(const int* flag, void* dout,
                                                  size_t i_reg, size_t i_off) {
  int f32 = *flag;
  const float* in = scrp(dout, f32, i_reg, i_off);
  const int p = blockIdx.x * 64 + threadIdx.x;
  const int n = blockIdx.y;
  const float* ip = in + (size_t)n * K2L * HWh + p;
  float v[K2L], m = -1e30f;
  #pragma unroll
  for (int k = 0; k < K2L; ++k) { v[k] = ip[(size_t)k * HWh]; m = fmaxf(m, v[k]); }
  float s = 0.f;
  #pragma unroll
  for (int k = 0; k < K2L; ++k) { v[k] = __expf(v[k] - m); s += v[k]; }
  const float inv = 1.0f / s;
  const size_t g = (size_t)n * K2L * HWh + p;
  if (f32) {
    float* o = (float*)dout;
    #pragma unroll
    for (int k = 0; k < K2L; ++k) o[g + (size_t)k * HWh] = v[k] * inv;
  } else {
    bf16* o = (bf16*)dout;
    #pragma unroll
    for (int k = 0; k < K2L; ++k) o[g + (size_t)k * HWh] = fromfloat<bf16>(v[k] * inv);
  }
}

// ---------------------------------------------------------------------------
// s=1 CARAFE fused residual with in-kernel softmax of the raw 3x3 mask:
// out = 2*feat - sum_{3x3} feat_pad * softmax(rawmask)
// ---------------------------------------------------------------------------
template<typename FT, typename OT, int FINAL>
__device__ void carafe1_body(const FT* __restrict__ feat, const float* __restrict__ rawm,
                             void* dout, size_t out_reg, float* __restrict__ outscr,
                             int C, int CPB, int numCG) {
  const int tid = threadIdx.x;
  const int tx = tid & 15, ty = tid >> 4;
  const int bx = blockIdx.x * 16, by = blockIdx.y * 16;
  const int n = blockIdx.z / numCG, cg = blockIdx.z % numCG;
  const int x = bx + tx, y = by + ty;
  const size_t pix = (size_t)y * Ww + x;

  float mv[9], m = -1e30f;
  #pragma unroll
  for (int k = 0; k < 9; ++k) {
    mv[k] = rawm[((size_t)n * 9 + k) * HWh + pix];
    m = fmaxf(m, mv[k]);
  }
  float s = 0.f;
  #pragma unroll
  for (int k = 0; k < 9; ++k) { mv[k] = __expf(mv[k] - m); s += mv[k]; }
  const float inv = 1.0f / s;
  #pragma unroll
  for (int k = 0; k < 9; ++k) mv[k] *= inv;

  const int c0 = cg * CPB;
  for (int c = c0; c < c0 + CPB; ++c) {
    const FT* fp = feat + ((size_t)n * C + c) * HWh;
    float acc = 0.f, center = 0.f;
    #pragma unroll
    for (int dy = -1; dy <= 1; ++dy)
      #pragma unroll
      for (int dx = -1; dx <= 1; ++dx) {
        int yy = y + dy, xx = x + dx;
        float fv = 0.f;
        if (yy >= 0 && yy < Hh && xx >= 0 && xx < Ww) fv = tofloat(fp[yy * Ww + xx]);
        if (dy == 0 && dx == 0) center = fv;
        acc = fmaf(fv, mv[(dy + 1) * 3 + (dx + 1)], acc);
      }
    float r = 2.f * center - acc;
    const size_t li = ((size_t)n * C + c) * HWh + pix;
    if (FINAL) ((OT*)dout)[out_reg + li] = fromfloat<OT>(r);
    else       outscr[li] = r;
  }
}

__global__ __launch_bounds__(256) void carafe1s_k(const int* flag, void* dout,
    size_t f_reg, size_t f_off, size_t m_reg, size_t m_off, size_t o_reg, size_t o_off,
    int C, int CPB, int numCG) {
  int f32 = *flag;
  carafe1_body<float, float, 0>(scrp(dout, f32, f_reg, f_off), scrp(dout, f32, m_reg, m_off),
                                dout, 0, scrp(dout, f32, o_reg, o_off), C, CPB, numCG);
}

__global__ __launch_bounds__(256) void carafe1f_k(const int* flag, void* dout, const void* feat,
    size_t m_reg, size_t m_off, size_t out_reg, int C, int CPB, int numCG) {
  int f32 = *flag;
  const float* m = scrp(dout, f32, m_reg, m_off);
  if (f32) carafe1_body<float, float, 1>((const float*)feat, m, dout, out_reg, nullptr, C, CPB, numCG);
  else     carafe1_body<bf16, bf16, 1>((const bf16*)feat, m, dout, out_reg, nullptr, C, CPB, numCG);
}

// ---------------------------------------------------------------------------
// s=2 CARAFE upsample (k=5). NORM: softmax raw mask in-kernel.
// ADDMODE: 0 none, 1 addend = raw mask channel c (s9' fusion), 2 addend buf.
// ---------------------------------------------------------------------------
template<typename FT, typename MT, typename OT, int NORM, int ADDMODE, int FINAL>
__device__ void carafe2_body(const FT* __restrict__ feat, const MT* __restrict__ mask,
                             const float* __restrict__ addend, void* dout, size_t out_reg,
                             float* __restrict__ outscr, int C, int CPB, int numCG) {
  __shared__ float ft[8][144];
  const int tid = threadIdx.x;
  const int tx = tid & 15, ty = tid >> 4;
  const int bx = blockIdx.x * 16, by = blockIdx.y * 16;
  const int n = blockIdx.z / numCG, cg = blockIdx.z % numCG;
  const int x = bx + tx, y = by + ty;
  const size_t pix = (size_t)y * Ww + x;

  float mv[25];
  #pragma unroll
  for (int k = 0; k < 25; ++k)
    mv[k] = tofloat(mask[((size_t)n * 25 + k) * HWh + pix]);
  float rawv[25];
  if (ADDMODE == 1) {
    #pragma unroll
    for (int k = 0; k < 25; ++k) rawv[k] = mv[k];
  }
  if (NORM) {
    float m = -1e30f;
    #pragma unroll
    for (int k = 0; k < 25; ++k) m = fmaxf(m, mv[k]);
    float s = 0.f;
    #pragma unroll
    for (int k = 0; k < 25; ++k) { mv[k] = __expf(mv[k] - m); s += mv[k]; }
    const float inv = 1.0f / s;
    #pragma unroll
    for (int k = 0; k < 25; ++k) mv[k] *= inv;
  }

  const int fy0 = (by >> 1) - 2, fx0 = (bx >> 1) - 2;   // 12x12 feat tile origin
  const int fyb = (ty >> 1) + 2, fxb = (tx >> 1) + 2;
  const int c0 = cg * CPB;
  const int cend = (c0 + CPB < C) ? c0 + CPB : C;

  for (int cb = c0; cb < cend; cb += 8) {
    const int lim = (cend - cb < 8) ? (cend - cb) : 8;
    __syncthreads();
    for (int i = tid; i < lim * 144; i += 256) {
      int cc = i / 144, r = i % 144, fy = r / 12, fx = r % 12;
      int gy = fy0 + fy, gx = fx0 + fx;
      float v = 0.f;
      if (gy >= 0 && gy < Hl && gx >= 0 && gx < Wl)
        v = tofloat(feat[((size_t)n * C + cb + cc) * HWl + gy * Wl + gx]);
      ft[cc][r] = v;
    }
    __syncthreads();
    for (int cc = 0; cc < lim; ++cc) {
      float s = 0.f;
      #pragma unroll
      for (int ki = 0; ki < 5; ++ki)
        #pragma unroll
        for (int kj = 0; kj < 5; ++kj)
          s = fmaf(ft[cc][(fyb + ki - 2) * 12 + (fxb + kj - 2)], mv[ki * 5 + kj], s);
      const int c = cb + cc;
      const size_t li = ((size_t)n * C + c) * HWh + pix;
      float r = s;
      if (ADDMODE == 1) r = rawv[c] + s;
      if (ADDMODE == 2) r = addend[li] + s;
      if (FINAL) ((OT*)dout)[out_reg + li] = fromfloat<OT>(r);
      else       outscr[li] = r;
    }
  }
}

// s9': feat f32, raw mask f32 (softmax in-kernel), addend = raw mask itself
__global__ __launch_bounds__(256) void carafe2s_k(const int* flag, void* dout,
    size_t f_reg, size_t f_off, size_t m_reg, size_t m_off, size_t o_reg, size_t o_off,
    int C, int CPB, int numCG) {
  int f32 = *flag;
  carafe2_body<float, float, float, 1, 1, 0>(scrp(dout, f32, f_reg, f_off),
      scrp(dout, f32, m_reg, m_off), nullptr, dout, 0, scrp(dout, f32, o_reg, o_off),
      C, CPB, numCG);
}

// s11: feat/addend/out f32 scratch, mask = final output 0 (dtype by flag)
__global__ __launch_bounds__(256) void carafe2m_k(const int* flag, void* dout,
    size_t f_reg, size_t f_off, size_t a_reg, size_t a_off, size_t o_reg, size_t o_off,
    int C, int CPB, int numCG) {
  int f32 = *flag;
  const float* f = scrp(dout, f32, f_reg, f_off);
  const float* a = scrp(dout, f32, a_reg, a_off);
  float* o = scrp(dout, f32, o_reg, o_off);
  if (f32) carafe2_body<float, float, float, 0, 2, 0>(f, (const float*)dout, a, dout, 0, o, C, CPB, numCG);
  else     carafe2_body<float, bf16, float, 0, 2, 0>(f, (const bf16*)dout, a, dout, 0, o, C, CPB, numCG);
}

// s13: feat = input, mask = final output 0, out = final out_lr
__global__ __launch_bounds__(256) void carafe2f_k(const int* flag, void* dout, const void* feat,
    size_t out_reg, int C, int CPB, int numCG) {
  int f32 = *flag;
  if (f32) carafe2_body<float, float, float, 0, 0, 1>((const float*)feat, (const float*)dout,
      nullptr, dout, out_reg, nullptr, C, CPB, numCG);
  else     carafe2_body<bf16, bf16, bf16, 0, 0, 1>((const bf16*)feat, (const bf16*)dout,
      nullptr, dout, out_reg, nullptr, C, CPB, numCG);
}

// ---------------------------------------------------------------------------
extern "C" void kernel_launch(void* const* d_in, const int* in_sizes, int n_in,
                              void* d_out, int out_size, void* d_ws, size_t ws_size,
                              hipStream_t stream) {
  const void* hr_feat = d_in[0];
  const void* lr_feat = d_in[1];
  int* flag = (int*)d_ws;  // only 4 bytes of ws used

  // 0. dtype detect
  detect_dtype<<<1, 256, 0, stream>>>(hr_feat, flag);
  // 1. weight prep -> arena A weight slots
  prep_weights<<<64, 256, 0, stream>>>(flag, d_out, d_in[2], d_in[3], d_in[4], d_in[5],
                                       d_in[6], d_in[7], d_in[8], d_in[9]);
  // 2. chf = conv1x1(hr_feat) -> A; clf = conv1x1(lr_feat) -> B
  conv1x1_k<<<dim3(HWh / 512, Nn, 4), 256, 0, stream>>>(flag, d_out, hr_feat, A_WHR, A_BHR, OFF_LR, A_CHF, HWh);
  conv1x1_k<<<dim3(HWl / 512, Nn, 4), 256, 0, stream>>>(flag, d_out, lr_feat, A_WLR, A_BLR, OFF_HR, B_CLF, HWl);
  // 3. mask_hr_hr = conv3x3(chf, enc2) -> B  (grid z = 4n x 3 ko-groups)
  conv3x3_k<K2H, 3><<<dim3(8, 8, Nn * 3), 256, 0, stream>>>(flag, d_out, OFF_LR, A_CHF, A_WENC2, A_BENC2, OFF_HR, B_MHRHR, Hh, Ww);
  // 5'. chf2 = 2*chf - carafe_s1(chf, softmax(mask_hr_hr)) -> B  [fused s4+s5]
  carafe1s_k<<<dim3(8, 8, Nn * 4), 256, 0, stream>>>(flag, d_out, OFF_LR, A_CHF, OFF_HR, B_MHRHR, OFF_HR, B_CHF2, Cc, 16, 4);
  // 6. mask_lr_hr = conv3x3(chf2, enc) -> A (chf dead)  (z = 4n x 5 groups)
  conv3x3_k<K2L, 5><<<dim3(8, 8, Nn * 5), 256, 0, stream>>>(flag, d_out, OFF_HR, B_CHF2, A_WENC, A_BENC, OFF_LR, A_MLRHR, Hh, Ww);
  // 7. m_lr_ll = conv3x3(clf, enc) -> A ; clf_e2 = conv3x3(clf, enc2) -> A
  conv3x3_k<K2L, 5><<<dim3(4, 4, Nn * 5), 256, 0, stream>>>(flag, d_out, OFF_HR, B_CLF, A_WENC, A_BENC, OFF_LR, A_MLRLL, Hl, Wl);
  conv3x3_k<K2H, 3><<<dim3(4, 4, Nn * 3), 256, 0, stream>>>(flag, d_out, OFF_HR, B_CLF, A_WENC2, A_BENC2, OFF_LR, A_CLFE2, Hl, Wl);
  // 9'. mask_lr = mask_lr_hr + carafe_s2(m_lr_ll, softmax(mask_lr_hr)) -> B  [fused s8+s9]
  carafe2s_k<<<dim3(8, 8, Nn * 4), 256, 0, stream>>>(flag, d_out, OFF_LR, A_MLRLL, OFF_LR, A_MLRHR, OFF_HR, B_MLR, K2L, 7, 4);
  // 10. mask_lr_out = softmax(mask_lr) -> FINAL output 0
  softmax25_k<<<dim3(HWh / 64, Nn), 64, 0, stream>>>(flag, d_out, OFF_HR, B_MLR);
  // 11. mask_hr = mask_hr_hr + carafe_s2(clf_e2, mask_lr_out) -> A (mlrhr dead)
  carafe2m_k<<<dim3(8, 8, Nn * 3), 256, 0, stream>>>(flag, d_out, OFF_LR, A_CLFE2, OFF_HR, B_MHRHR, OFF_LR, A_MHR2, K2H, 3, 3);
  // 14'. hr_out = 2*hr_feat - carafe_s1(hr_feat, softmax(mask_hr)) -> FINAL out_hr  [fused s12+s14]
  carafe1f_k<<<dim3(8, 8, Nn * 8), 256, 0, stream>>>(flag, d_out, hr_feat, OFF_LR, A_MHR2, OFF_HR, Ci, 32, 8);
  // 13 (last). lr_out = carafe_s2(lr_feat, mask_lr_out) -> FINAL out_lr (overwrites arena A)
  carafe2f_k<<<dim3(8, 8, Nn * 8), 256, 0, stream>>>(flag, d_out, lr_feat, OFF_LR, Ci, 32, 8);
}